// Round 11
// baseline (392.339 us; speedup 1.0000x reference)
//
#include <hip/hip_runtime.h>
#include <hip/hip_bf16.h>
#include <stdint.h>

#define NN 8192
#define IN_DIM 343
#define IN_PAD 352
#define HID 1000
#define HID_PAD 1024
#define EPS 1e-5f
#define BK2 32            // GEMM2 K-step

typedef __attribute__((ext_vector_type(8))) short bf16x8;
typedef __attribute__((ext_vector_type(4))) float f32x4;

static __device__ __forceinline__ unsigned short f2bf(float f) {
    union { float f; unsigned int u; } v; v.f = f;
    unsigned int u = v.u;
    unsigned int r = (u + 0x7FFFu + ((u >> 16) & 1u)) >> 16;   // RNE
    return (unsigned short)r;
}

static __device__ __forceinline__ unsigned cvt_pk_bf16(float lo, float hi) {
    unsigned r;
    asm("v_cvt_pk_bf16_f32 %0, %1, %2" : "=v"(r) : "v"(lo), "v"(hi));
    return r;
}

// ---------------- conversion kernels ----------------

__global__ __launch_bounds__(256) void k_cvt_feat(const float* __restrict__ src,
                                                  unsigned short* __restrict__ dst) {
    int idx = blockIdx.x * blockDim.x + threadIdx.x;
    if (idx >= NN * IN_PAD) return;
    int row = idx / IN_PAD;
    int col = idx - row * IN_PAD;
    dst[idx] = (col < IN_DIM) ? f2bf(src[(size_t)row * IN_DIM + col]) : 0;
}

__global__ __launch_bounds__(256) void k_cvt_w1t(const float* __restrict__ W1,
                                                 unsigned short* __restrict__ dst) {
    int idx = blockIdx.x * blockDim.x + threadIdx.x;
    if (idx >= HID_PAD * IN_PAD) return;
    int n = idx / IN_PAD;
    int k = idx - n * IN_PAD;
    dst[idx] = (k < IN_DIM && n < HID) ? f2bf(W1[(size_t)k * HID + n]) : 0;
}

// ---------------- GEMM1: bf16 128x128 tile (m97 2-barrier structure) ----------------

__global__ void k_gemm_bf(const unsigned short* __restrict__ A,
                          const unsigned short* __restrict__ Bt,
                          unsigned short* __restrict__ Cout,
                          int M, int N, int K) {
    __shared__ unsigned short ldsA[128 * 32];
    __shared__ unsigned short ldsB[128 * 32];

    const int tid = threadIdx.x;
    const int nbn = N >> 7;
    const int bm = blockIdx.x / nbn;
    const int bn = blockIdx.x - bm * nbn;

    const int wid = tid >> 6, lane = tid & 63;
    const int wr = wid >> 1, wc = wid & 1;
    const int lr = lane & 15, lg = lane >> 4;

    f32x4 acc[4][4] = {};

    const int r0 = tid >> 2, s0 = tid & 3;
    const unsigned short* Ag0 = A + ((size_t)bm * 128 + r0) * K + s0 * 8;
    const unsigned short* Ag1 = A + ((size_t)bm * 128 + 64 + r0) * K + s0 * 8;
    const unsigned short* Bg0 = Bt + ((size_t)bn * 128 + r0) * K + s0 * 8;
    const unsigned short* Bg1 = Bt + ((size_t)bn * 128 + 64 + r0) * K + s0 * 8;
    unsigned short* lA0 = ldsA + (size_t)(wid * 64) * 8;
    unsigned short* lA1 = ldsA + (size_t)(256 + wid * 64) * 8;
    unsigned short* lB0 = ldsB + (size_t)(wid * 64) * 8;
    unsigned short* lB1 = ldsB + (size_t)(256 + wid * 64) * 8;

    for (int kt = 0; kt < K; kt += 32) {
        __builtin_amdgcn_global_load_lds(
            (const __attribute__((address_space(1))) void*)(Ag0 + kt),
            (__attribute__((address_space(3))) void*)lA0, 16, 0, 0);
        __builtin_amdgcn_global_load_lds(
            (const __attribute__((address_space(1))) void*)(Ag1 + kt),
            (__attribute__((address_space(3))) void*)lA1, 16, 0, 0);
        __builtin_amdgcn_global_load_lds(
            (const __attribute__((address_space(1))) void*)(Bg0 + kt),
            (__attribute__((address_space(3))) void*)lB0, 16, 0, 0);
        __builtin_amdgcn_global_load_lds(
            (const __attribute__((address_space(1))) void*)(Bg1 + kt),
            (__attribute__((address_space(3))) void*)lB1, 16, 0, 0);
        __syncthreads();

        bf16x8 af[4], bfr[4];
#pragma unroll
        for (int i = 0; i < 4; i++) {
            af[i]  = *(const bf16x8*)&ldsA[((wr * 64 + i * 16 + lr) * 32) + lg * 8];
            bfr[i] = *(const bf16x8*)&ldsB[((wc * 64 + i * 16 + lr) * 32) + lg * 8];
        }
#pragma unroll
        for (int i = 0; i < 4; i++)
#pragma unroll
            for (int j = 0; j < 4; j++)
                acc[i][j] = __builtin_amdgcn_mfma_f32_16x16x32_bf16(af[i], bfr[j], acc[i][j], 0, 0, 0);
        __syncthreads();
    }

    const int row0 = bm * 128 + wr * 64;
    const int col0 = bn * 128 + wc * 64;
#pragma unroll
    for (int mi = 0; mi < 4; mi++) {
#pragma unroll
        for (int ni = 0; ni < 4; ni++) {
            int col = col0 + ni * 16 + lr;
#pragma unroll
            for (int j = 0; j < 4; j++) {
                int row = row0 + mi * 16 + lg * 4 + j;
                Cout[(size_t)row * N + col] = f2bf(acc[mi][ni][j]);
            }
        }
    }
}

// ---------------- GEMM2: A-only LDS (dbuf, swizzled), B direct global->reg ----------------
// h1 = relu(adj_fp32 * xwt^T + b1). 128x128 tile, BK=32, 4 waves.
// LDS holds ONLY the fp32 A tile (2 x 16 KB dbuf). B fragments are loaded straight
// from L2/L3-resident xwt into registers (per-wave private, depth-1 prefetch, no
// barrier coupling). Counted vmcnt(8): per iter each wave issues 4 A-gloads + 4
// B-reg-loads; own-wait-then-barrier => all waves' A staged. Conflicts on B: zero.
// A XOR-swizzle + XCD swizzle: R6-verified.

#define G2_STAGE_A(BUF, KT)                                                                  \
  {                                                                                          \
    _Pragma("unroll")                                                                        \
    for (int q = 0; q < 4; q++) {                                                            \
      const int r = q * 32 + wid * 8 + (lane >> 3);                                          \
      __builtin_amdgcn_global_load_lds(                                                      \
          (const __attribute__((address_space(1))) void*)                                    \
              (Abase + (size_t)r * NN + (KT) + aslot * 4),                                   \
          (__attribute__((address_space(3))) void*)(&ldsAf[BUF][0] + q * 1024 + wid * 256),  \
          16, 0, 0);                                                                         \
    }                                                                                        \
  }

#define G2_LOAD_B(REG, KT)                                                                   \
  {                                                                                          \
    _Pragma("unroll")                                                                        \
    for (int j = 0; j < 4; j++)                                                              \
      REG[j] = *(const bf16x8*)(Bw + (size_t)j * 16 * NN + (KT));                            \
  }

#define G2_COMPUTE(BUF, BREG)                                                                \
  {                                                                                          \
    bf16x8 af[4];                                                                            \
    _Pragma("unroll")                                                                        \
    for (int i = 0; i < 4; i++) {                                                            \
      const int r = wr * 64 + i * 16 + lr;                                                   \
      const int p0 = (lg * 2)     ^ (lr & 7);                                                \
      const int p1 = (lg * 2 + 1) ^ (lr & 7);                                                \
      const f32x4 lo = *(const f32x4*)&ldsAf[BUF][r * 32 + p0 * 4];                          \
      const f32x4 hi = *(const f32x4*)&ldsAf[BUF][r * 32 + p1 * 4];                          \
      union { uint32_t u[4]; bf16x8 v; } pk;                                                 \
      pk.u[0] = cvt_pk_bf16(lo[0], lo[1]);                                                   \
      pk.u[1] = cvt_pk_bf16(lo[2], lo[3]);                                                   \
      pk.u[2] = cvt_pk_bf16(hi[0], hi[1]);                                                   \
      pk.u[3] = cvt_pk_bf16(hi[2], hi[3]);                                                   \
      af[i] = pk.v;                                                                          \
    }                                                                                        \
    __builtin_amdgcn_s_setprio(1);                                                           \
    _Pragma("unroll")                                                                        \
    for (int i = 0; i < 4; i++)                                                              \
      _Pragma("unroll")                                                                      \
      for (int j = 0; j < 4; j++)                                                            \
        acc[i][j] = __builtin_amdgcn_mfma_f32_16x16x32_bf16(af[i], BREG[j], acc[i][j], 0, 0, 0); \
    __builtin_amdgcn_s_setprio(0);                                                           \
  }

__global__ __launch_bounds__(256, 3) void k_gemm2(const float* __restrict__ A,
                                                  const unsigned short* __restrict__ Bt,
                                                  const float* __restrict__ b1,
                                                  float* __restrict__ H) {
    __shared__ float ldsAf[2][128 * BK2];     // 2 x 16 KB (A only)

    const int tid = threadIdx.x;
    const int wg = blockIdx.x;                   // 512 blocks = 64 bm x 8 bn
    const int swz = (wg & 7) * 64 + (wg >> 3);   // bijective; XCD x owns bm in [8x,8x+8)
    const int bm = swz >> 3;
    const int bn = swz & 7;

    const int wid = tid >> 6, lane = tid & 63;
    const int wr = wid >> 1, wc = wid & 1;
    const int lr = lane & 15, lg = lane >> 4;

    f32x4 acc[4][4] = {};

    const float* Abase = A + ((size_t)bm * 128) * NN;
    // per-lane B base: row = bn*128 + wc*64 + lr (+j*16), col = kt + lg*8
    const unsigned short* Bw = Bt + ((size_t)(bn * 128 + wc * 64 + lr)) * NN + lg * 8;

    const int aslot = (lane & 7) ^ (lane >> 3);   // A swizzle: row&7 = lane>>3

    bf16x8 brA[4], brB[4];

    // prologue: A(0) -> buf0, B(0) -> brA   (8 vmem in flight)
    G2_STAGE_A(0, 0);
    G2_LOAD_B(brA, 0);

    for (int kt = 0; kt < NN; kt += 64) {
        // even tile t: stage A(t+1)->buf1, load B(t+1)->brB (always valid: kt+32 <= 8160)
        G2_STAGE_A(1, kt + 32);
        G2_LOAD_B(brB, kt + 32);
        asm volatile("s_waitcnt vmcnt(8)" ::: "memory");   // A(t),B(t) complete (own)
        __builtin_amdgcn_sched_barrier(0);
        __builtin_amdgcn_s_barrier();                      // => all waves' A(t) staged
        __builtin_amdgcn_sched_barrier(0);
        G2_COMPUTE(0, brA);
        __builtin_amdgcn_s_barrier();                      // buf0 free for overwrite
        __builtin_amdgcn_sched_barrier(0);

        // odd tile t+1
        if (kt + 64 < NN) {
            G2_STAGE_A(0, kt + 64);
            G2_LOAD_B(brA, kt + 64);
            asm volatile("s_waitcnt vmcnt(8)" ::: "memory");
        } else {
            asm volatile("s_waitcnt vmcnt(0)" ::: "memory");
        }
        __builtin_amdgcn_sched_barrier(0);
        __builtin_amdgcn_s_barrier();
        __builtin_amdgcn_sched_barrier(0);
        G2_COMPUTE(1, brB);
        __builtin_amdgcn_s_barrier();
        __builtin_amdgcn_sched_barrier(0);
    }

    // epilogue: bias + relu fused, fp32 store
    const int row0 = bm * 128 + wr * 64;
    const int col0 = bn * 128 + wc * 64;
#pragma unroll
    for (int mi = 0; mi < 4; mi++) {
#pragma unroll
        for (int ni = 0; ni < 4; ni++) {
            int col = col0 + ni * 16 + lr;
            float b = (col < HID) ? b1[col] : 0.f;
#pragma unroll
            for (int j = 0; j < 4; j++) {
                int row = row0 + mi * 16 + lg * 4 + j;
                float v = acc[mi][ni][j] + b;
                v = v > 0.f ? v : 0.f;
                H[(size_t)row * HID_PAD + col] = v;
            }
        }
    }
}

// ---------------- LayerNorm + head ----------------
__global__ __launch_bounds__(256) void k_ln_head(const float* __restrict__ h1p,
                                                 const float* __restrict__ gamma,
                                                 const float* __restrict__ beta,
                                                 const float* __restrict__ Wm,
                                                 const float* __restrict__ bm,
                                                 float* __restrict__ out) {
    const int row = blockIdx.x;
    const int t = threadIdx.x;
    const float* hr = h1p + (size_t)row * HID_PAD;

    float v[4];
    float s = 0.f, ss = 0.f;
#pragma unroll
    for (int i = 0; i < 4; i++) {
        int ix = t + i * 256;
        float x = (ix < HID) ? hr[ix] : 0.f;
        v[i] = x; s += x; ss += x * x;
    }
#pragma unroll
    for (int o = 32; o > 0; o >>= 1) { s += __shfl_down(s, o); ss += __shfl_down(ss, o); }

    __shared__ float rs[8], rss[8];
    const int wid = t >> 6, lane = t & 63;
    if (lane == 0) { rs[wid] = s; rss[wid] = ss; }
    __syncthreads();
    if (t == 0) {
        float a = 0.f, b = 0.f;
        for (int w = 0; w < 4; w++) { a += rs[w]; b += rss[w]; }
        rs[4] = a; rss[4] = b;
    }
    __syncthreads();
    const float mean = rs[4] * (1.0f / HID);
    const float var = rss[4] * (1.0f / HID) - mean * mean;
    const float rstd = rsqrtf(var + EPS);

    float q0 = 0.f, q1 = 0.f, q2 = 0.f, q3 = 0.f;
#pragma unroll
    for (int i = 0; i < 4; i++) {
        int ix = t + i * 256;
        if (ix < HID) {
            float hn = (v[i] - mean) * rstd * gamma[ix] + beta[ix];
            const float* w = Wm + (size_t)ix * 4;
            q0 += hn * w[0]; q1 += hn * w[1]; q2 += hn * w[2]; q3 += hn * w[3];
        }
    }
#pragma unroll
    for (int o = 32; o > 0; o >>= 1) {
        q0 += __shfl_down(q0, o); q1 += __shfl_down(q1, o);
        q2 += __shfl_down(q2, o); q3 += __shfl_down(q3, o);
    }
    __shared__ float rp[4][4];
    if (lane == 0) { rp[wid][0] = q0; rp[wid][1] = q1; rp[wid][2] = q2; rp[wid][3] = q3; }
    __syncthreads();
    if (t < 4) {
        float a = rp[0][t] + rp[1][t] + rp[2][t] + rp[3][t] + bm[t];
        out[(size_t)row * 4 + t] = a;
    }
}

// ---------------- launcher ----------------
extern "C" void kernel_launch(void* const* d_in, const int* in_sizes, int n_in,
                              void* d_out, int out_size, void* d_ws, size_t ws_size,
                              hipStream_t stream) {
    const float* adj      = (const float*)d_in[0];
    const float* features = (const float*)d_in[1];
    const float* W1       = (const float*)d_in[2];
    const float* b1       = (const float*)d_in[3];
    const float* gamma    = (const float*)d_in[4];
    const float* beta     = (const float*)d_in[5];
    const float* Wm       = (const float*)d_in[6];
    const float* bm       = (const float*)d_in[7];
    float* out = (float*)d_out;

    uint8_t* ws = (uint8_t*)d_ws;
    unsigned short* feat_p = (unsigned short*)ws;                 //  5,767,168 B
    unsigned short* w1t    = (unsigned short*)(ws + 5767168);     //    720,896 B
    unsigned short* xwt    = (unsigned short*)(ws + 6488064);     // 16,777,216 B
    float*          h1     = (float*)(ws + 23265280);             // 33,554,432 B (~57 MB total)

    k_cvt_feat<<<(NN * IN_PAD + 255) / 256, 256, 0, stream>>>(features, feat_p);
    k_cvt_w1t<<<(HID_PAD * IN_PAD + 255) / 256, 256, 0, stream>>>(W1, w1t);

    // GEMM1: xwt[1024][8192] = w1t * feat_p^T  (bf16 out)
    k_gemm_bf<<<(HID_PAD / 128) * (NN / 128), 256, 0, stream>>>(
        w1t, feat_p, xwt, HID_PAD, NN, IN_PAD);

    // GEMM2: h1 = relu(adj * xwt^T + b1); A-only LDS, B direct from L2/L3
    k_gemm2<<<(NN / 128) * (HID_PAD / 128), 256, 0, stream>>>(adj, xwt, b1, h1);

    k_ln_head<<<NN, 256, 0, stream>>>(h1, gamma, beta, Wm, bm, out);
}

// Round 12
// 260.816 us; speedup vs baseline: 1.5043x; 1.5043x over previous
//
#include <hip/hip_runtime.h>
#include <hip/hip_bf16.h>
#include <stdint.h>

#define NN 8192
#define IN_DIM 343
#define IN_PAD 352
#define HID 1000
#define HID_PAD 1024
#define EPS 1e-5f
#define BK2 64            // GEMM2 K-step (halves barrier count vs BK=32)

typedef __attribute__((ext_vector_type(8))) short bf16x8;
typedef __attribute__((ext_vector_type(4))) float f32x4;

static __device__ __forceinline__ unsigned short f2bf(float f) {
    union { float f; unsigned int u; } v; v.f = f;
    unsigned int u = v.u;
    unsigned int r = (u + 0x7FFFu + ((u >> 16) & 1u)) >> 16;   // RNE
    return (unsigned short)r;
}

static __device__ __forceinline__ unsigned cvt_pk_bf16(float lo, float hi) {
    unsigned r;
    asm("v_cvt_pk_bf16_f32 %0, %1, %2" : "=v"(r) : "v"(lo), "v"(hi));
    return r;
}

// ---------------- conversion kernels ----------------

__global__ __launch_bounds__(256) void k_cvt_feat(const float* __restrict__ src,
                                                  unsigned short* __restrict__ dst) {
    int idx = blockIdx.x * blockDim.x + threadIdx.x;
    if (idx >= NN * IN_PAD) return;
    int row = idx / IN_PAD;
    int col = idx - row * IN_PAD;
    dst[idx] = (col < IN_DIM) ? f2bf(src[(size_t)row * IN_DIM + col]) : 0;
}

__global__ __launch_bounds__(256) void k_cvt_w1t(const float* __restrict__ W1,
                                                 unsigned short* __restrict__ dst) {
    int idx = blockIdx.x * blockDim.x + threadIdx.x;
    if (idx >= HID_PAD * IN_PAD) return;
    int n = idx / IN_PAD;
    int k = idx - n * IN_PAD;
    dst[idx] = (k < IN_DIM && n < HID) ? f2bf(W1[(size_t)k * HID + n]) : 0;
}

// ---------------- GEMM1: bf16 128x128 tile (m97 2-barrier structure) ----------------

__global__ void k_gemm_bf(const unsigned short* __restrict__ A,
                          const unsigned short* __restrict__ Bt,
                          unsigned short* __restrict__ Cout,
                          int M, int N, int K) {
    __shared__ unsigned short ldsA[128 * 32];
    __shared__ unsigned short ldsB[128 * 32];

    const int tid = threadIdx.x;
    const int nbn = N >> 7;
    const int bm = blockIdx.x / nbn;
    const int bn = blockIdx.x - bm * nbn;

    const int wid = tid >> 6, lane = tid & 63;
    const int wr = wid >> 1, wc = wid & 1;
    const int lr = lane & 15, lg = lane >> 4;

    f32x4 acc[4][4] = {};

    const int r0 = tid >> 2, s0 = tid & 3;
    const unsigned short* Ag0 = A + ((size_t)bm * 128 + r0) * K + s0 * 8;
    const unsigned short* Ag1 = A + ((size_t)bm * 128 + 64 + r0) * K + s0 * 8;
    const unsigned short* Bg0 = Bt + ((size_t)bn * 128 + r0) * K + s0 * 8;
    const unsigned short* Bg1 = Bt + ((size_t)bn * 128 + 64 + r0) * K + s0 * 8;
    unsigned short* lA0 = ldsA + (size_t)(wid * 64) * 8;
    unsigned short* lA1 = ldsA + (size_t)(256 + wid * 64) * 8;
    unsigned short* lB0 = ldsB + (size_t)(wid * 64) * 8;
    unsigned short* lB1 = ldsB + (size_t)(256 + wid * 64) * 8;

    for (int kt = 0; kt < K; kt += 32) {
        __builtin_amdgcn_global_load_lds(
            (const __attribute__((address_space(1))) void*)(Ag0 + kt),
            (__attribute__((address_space(3))) void*)lA0, 16, 0, 0);
        __builtin_amdgcn_global_load_lds(
            (const __attribute__((address_space(1))) void*)(Ag1 + kt),
            (__attribute__((address_space(3))) void*)lA1, 16, 0, 0);
        __builtin_amdgcn_global_load_lds(
            (const __attribute__((address_space(1))) void*)(Bg0 + kt),
            (__attribute__((address_space(3))) void*)lB0, 16, 0, 0);
        __builtin_amdgcn_global_load_lds(
            (const __attribute__((address_space(1))) void*)(Bg1 + kt),
            (__attribute__((address_space(3))) void*)lB1, 16, 0, 0);
        __syncthreads();

        bf16x8 af[4], bfr[4];
#pragma unroll
        for (int i = 0; i < 4; i++) {
            af[i]  = *(const bf16x8*)&ldsA[((wr * 64 + i * 16 + lr) * 32) + lg * 8];
            bfr[i] = *(const bf16x8*)&ldsB[((wc * 64 + i * 16 + lr) * 32) + lg * 8];
        }
#pragma unroll
        for (int i = 0; i < 4; i++)
#pragma unroll
            for (int j = 0; j < 4; j++)
                acc[i][j] = __builtin_amdgcn_mfma_f32_16x16x32_bf16(af[i], bfr[j], acc[i][j], 0, 0, 0);
        __syncthreads();
    }

    const int row0 = bm * 128 + wr * 64;
    const int col0 = bn * 128 + wc * 64;
#pragma unroll
    for (int mi = 0; mi < 4; mi++) {
#pragma unroll
        for (int ni = 0; ni < 4; ni++) {
            int col = col0 + ni * 16 + lr;
#pragma unroll
            for (int j = 0; j < 4; j++) {
                int row = row0 + mi * 16 + lg * 4 + j;
                Cout[(size_t)row * N + col] = f2bf(acc[mi][ni][j]);
            }
        }
    }
}

// ---------------- GEMM2: BK=64, 2-phase, XOR-swizzled (R6 base, half the barriers) ----------------
// h1 = relu(adj_fp32 * xwt^T + b1). 128x128 tile, 4 waves, 48 KB LDS (1 buffer, 3 blocks/CU).
// A fp32 [128][64]: 16 slots(16B)/row; stored slot = slot ^ (row&15) -> 2-way (free) reads.
// B bf16 [128][64]: 8 slots/row; stored slot = slot ^ (row&7) -> 2-way reads.
// Swizzle applied via pre-permuted GLOBAL source lane-address (rule #21), LDS dest linear.
// XCD swizzle: XCD x owns bm in [8x,8x+8) -> adj fetched ~once chip-wide.

__global__ __launch_bounds__(256, 3) void k_gemm2(const float* __restrict__ A,
                                                  const unsigned short* __restrict__ Bt,
                                                  const float* __restrict__ b1,
                                                  float* __restrict__ H) {
    __shared__ float          ldsAf[128 * BK2];     // 32 KB
    __shared__ unsigned short ldsBh[128 * BK2];     // 16 KB

    const int tid = threadIdx.x;
    const int wg = blockIdx.x;                   // 512 blocks = 64 bm x 8 bn
    const int swz = (wg & 7) * 64 + (wg >> 3);   // bijective; XCD x owns bm in [8x,8x+8)
    const int bm = swz >> 3;
    const int bn = swz & 7;

    const int wid = tid >> 6, lane = tid & 63;
    const int wr = wid >> 1, wc = wid & 1;
    const int lr = lane & 15, lg = lane >> 4;

    f32x4 acc[4][4] = {};

    const float* Abase = A + ((size_t)bm * 128) * NN;
    const unsigned short* Bbase = Bt + ((size_t)bn * 128) * NN;

    for (int kt = 0; kt < NN; kt += BK2) {
        // A: 8 instrs/wave x 1KB. chunk c = wid*8+q covers rows c*4+(lane>>4), 4 rows/instr.
        // source slot = (lane&15) ^ ((q&3)*4 + (lane>>4))   [row&15 = (q&3)*4 + (lane>>4)]
#pragma unroll
        for (int q = 0; q < 8; q++) {
            const int c = wid * 8 + q;
            const int r = c * 4 + (lane >> 4);
            const int aslot = (lane & 15) ^ ((q & 3) * 4 + (lane >> 4));
            __builtin_amdgcn_global_load_lds(
                (const __attribute__((address_space(1))) void*)
                    (Abase + (size_t)r * NN + kt + aslot * 4),
                (__attribute__((address_space(3))) void*)(ldsAf + c * 256),
                16, 0, 0);
        }
        // B: 4 instrs/wave x 1KB. chunk c = wid*4+q covers rows c*8+(lane>>3).
        // source slot = (lane&7) ^ (lane>>3)   [row&7 = lane>>3]
#pragma unroll
        for (int q = 0; q < 4; q++) {
            const int c = wid * 4 + q;
            const int r = c * 8 + (lane >> 3);
            const int bslot = (lane & 7) ^ (lane >> 3);
            __builtin_amdgcn_global_load_lds(
                (const __attribute__((address_space(1))) void*)
                    (Bbase + (size_t)r * NN + kt + bslot * 8),
                (__attribute__((address_space(3))) void*)(ldsBh + c * 512),
                16, 0, 0);
        }
        __syncthreads();

#pragma unroll
        for (int kk = 0; kk < 2; kk++) {
            bf16x8 af[4], bfr[4];
#pragma unroll
            for (int i = 0; i < 4; i++) {
                const int r = wr * 64 + i * 16 + lr;
                const int p0 = (kk * 8 + lg * 2)     ^ (r & 15);
                const int p1 = (kk * 8 + lg * 2 + 1) ^ (r & 15);
                const f32x4 lo = *(const f32x4*)&ldsAf[r * 64 + p0 * 4];
                const f32x4 hi = *(const f32x4*)&ldsAf[r * 64 + p1 * 4];
                union { uint32_t u[4]; bf16x8 v; } pk;
                pk.u[0] = cvt_pk_bf16(lo[0], lo[1]);
                pk.u[1] = cvt_pk_bf16(lo[2], lo[3]);
                pk.u[2] = cvt_pk_bf16(hi[0], hi[1]);
                pk.u[3] = cvt_pk_bf16(hi[2], hi[3]);
                af[i] = pk.v;
            }
#pragma unroll
            for (int j = 0; j < 4; j++) {
                const int r = wc * 64 + j * 16 + lr;
                const int p = (kk * 4 + lg) ^ (r & 7);
                bfr[j] = *(const bf16x8*)&ldsBh[r * 64 + p * 8];
            }
            __builtin_amdgcn_s_setprio(1);
#pragma unroll
            for (int i = 0; i < 4; i++)
#pragma unroll
                for (int j = 0; j < 4; j++)
                    acc[i][j] = __builtin_amdgcn_mfma_f32_16x16x32_bf16(af[i], bfr[j], acc[i][j], 0, 0, 0);
            __builtin_amdgcn_s_setprio(0);
        }
        __syncthreads();
    }

    // epilogue: bias + relu fused, fp32 store
    const int row0 = bm * 128 + wr * 64;
    const int col0 = bn * 128 + wc * 64;
#pragma unroll
    for (int mi = 0; mi < 4; mi++) {
#pragma unroll
        for (int ni = 0; ni < 4; ni++) {
            int col = col0 + ni * 16 + lr;
            float b = (col < HID) ? b1[col] : 0.f;
#pragma unroll
            for (int j = 0; j < 4; j++) {
                int row = row0 + mi * 16 + lg * 4 + j;
                float v = acc[mi][ni][j] + b;
                v = v > 0.f ? v : 0.f;
                H[(size_t)row * HID_PAD + col] = v;
            }
        }
    }
}

// ---------------- LayerNorm + head ----------------
__global__ __launch_bounds__(256) void k_ln_head(const float* __restrict__ h1p,
                                                 const float* __restrict__ gamma,
                                                 const float* __restrict__ beta,
                                                 const float* __restrict__ Wm,
                                                 const float* __restrict__ bm,
                                                 float* __restrict__ out) {
    const int row = blockIdx.x;
    const int t = threadIdx.x;
    const float* hr = h1p + (size_t)row * HID_PAD;

    float v[4];
    float s = 0.f, ss = 0.f;
#pragma unroll
    for (int i = 0; i < 4; i++) {
        int ix = t + i * 256;
        float x = (ix < HID) ? hr[ix] : 0.f;
        v[i] = x; s += x; ss += x * x;
    }
#pragma unroll
    for (int o = 32; o > 0; o >>= 1) { s += __shfl_down(s, o); ss += __shfl_down(ss, o); }

    __shared__ float rs[8], rss[8];
    const int wid = t >> 6, lane = t & 63;
    if (lane == 0) { rs[wid] = s; rss[wid] = ss; }
    __syncthreads();
    if (t == 0) {
        float a = 0.f, b = 0.f;
        for (int w = 0; w < 4; w++) { a += rs[w]; b += rss[w]; }
        rs[4] = a; rss[4] = b;
    }
    __syncthreads();
    const float mean = rs[4] * (1.0f / HID);
    const float var = rss[4] * (1.0f / HID) - mean * mean;
    const float rstd = rsqrtf(var + EPS);

    float q0 = 0.f, q1 = 0.f, q2 = 0.f, q3 = 0.f;
#pragma unroll
    for (int i = 0; i < 4; i++) {
        int ix = t + i * 256;
        if (ix < HID) {
            float hn = (v[i] - mean) * rstd * gamma[ix] + beta[ix];
            const float* w = Wm + (size_t)ix * 4;
            q0 += hn * w[0]; q1 += hn * w[1]; q2 += hn * w[2]; q3 += hn * w[3];
        }
    }
#pragma unroll
    for (int o = 32; o > 0; o >>= 1) {
        q0 += __shfl_down(q0, o); q1 += __shfl_down(q1, o);
        q2 += __shfl_down(q2, o); q3 += __shfl_down(q3, o);
    }
    __shared__ float rp[4][4];
    if (lane == 0) { rp[wid][0] = q0; rp[wid][1] = q1; rp[wid][2] = q2; rp[wid][3] = q3; }
    __syncthreads();
    if (t < 4) {
        float a = rp[0][t] + rp[1][t] + rp[2][t] + rp[3][t] + bm[t];
        out[(size_t)row * 4 + t] = a;
    }
}

// ---------------- launcher ----------------
extern "C" void kernel_launch(void* const* d_in, const int* in_sizes, int n_in,
                              void* d_out, int out_size, void* d_ws, size_t ws_size,
                              hipStream_t stream) {
    const float* adj      = (const float*)d_in[0];
    const float* features = (const float*)d_in[1];
    const float* W1       = (const float*)d_in[2];
    const float* b1       = (const float*)d_in[3];
    const float* gamma    = (const float*)d_in[4];
    const float* beta     = (const float*)d_in[5];
    const float* Wm       = (const float*)d_in[6];
    const float* bm       = (const float*)d_in[7];
    float* out = (float*)d_out;

    uint8_t* ws = (uint8_t*)d_ws;
    unsigned short* feat_p = (unsigned short*)ws;                 //  5,767,168 B
    unsigned short* w1t    = (unsigned short*)(ws + 5767168);     //    720,896 B
    unsigned short* xwt    = (unsigned short*)(ws + 6488064);     // 16,777,216 B
    float*          h1     = (float*)(ws + 23265280);             // 33,554,432 B (~57 MB total)

    k_cvt_feat<<<(NN * IN_PAD + 255) / 256, 256, 0, stream>>>(features, feat_p);
    k_cvt_w1t<<<(HID_PAD * IN_PAD + 255) / 256, 256, 0, stream>>>(W1, w1t);

    // GEMM1: xwt[1024][8192] = w1t * feat_p^T  (bf16 out)
    k_gemm_bf<<<(HID_PAD / 128) * (NN / 128), 256, 0, stream>>>(
        w1t, feat_p, xwt, HID_PAD, NN, IN_PAD);

    // GEMM2: h1 = relu(adj * xwt^T + b1); BK=64, swizzled, 2-phase
    k_gemm2<<<(NN / 128) * (HID_PAD / 128), 256, 0, stream>>>(adj, xwt, b1, h1);

    k_ln_head<<<NN, 256, 0, stream>>>(h1, gamma, beta, Wm, bm, out);
}